// Round 4
// baseline (488.926 us; speedup 1.0000x reference)
//
#include <hip/hip_runtime.h>
#include <math.h>

#define NJ 25          // joints (voxel channels)
#define NJP 32         // padded channel stride in transposed layout (128B, float4-aligned)
#define VD 32
#define VH 128
#define VW 128
#define MAXNI 14
#define TEMP 20.0f
#define NEGINF (-10000.0f)
#define DHW (VD*VH*VW)        // 524288
#define NCELL 4096            // 16^3 morton cells for the point sort
#define TINV_FLOATS 256       // reserved arena for tinv (needs ni*12=168; padded, NO overlap!)

// ---------------- Kernel A: invert the 14 init-bone affine transforms ----------------
__global__ void invert_tfs_kernel(const float* __restrict__ tfs,
                                  const int* __restrict__ bones,
                                  float* __restrict__ tinv, int ni) {
    int t = threadIdx.x;
    if (t >= ni) return;
    const float* T = tfs + (size_t)bones[t] * 16;
    double r00=T[0], r01=T[1], r02=T[2],  tx=T[3];
    double r10=T[4], r11=T[5], r12=T[6],  ty=T[7];
    double r20=T[8], r21=T[9], r22=T[10], tz=T[11];
    double c00 = r11*r22 - r12*r21;
    double c01 = r12*r20 - r10*r22;
    double c02 = r10*r21 - r11*r20;
    double det = r00*c00 + r01*c01 + r02*c02;
    double id  = 1.0/det;
    double i00 = c00*id;
    double i01 = (r02*r21 - r01*r22)*id;
    double i02 = (r01*r12 - r02*r11)*id;
    double i10 = c01*id;
    double i11 = (r00*r22 - r02*r20)*id;
    double i12 = (r02*r10 - r00*r12)*id;
    double i20 = c02*id;
    double i21 = (r01*r20 - r00*r21)*id;
    double i22 = (r00*r11 - r01*r10)*id;
    double itx = -(i00*tx + i01*ty + i02*tz);
    double ity = -(i10*tx + i11*ty + i12*tz);
    double itz = -(i20*tx + i21*ty + i22*tz);
    float* o = tinv + t*12;
    o[0]=(float)i00; o[1]=(float)i01; o[2] =(float)i02; o[3] =(float)itx;
    o[4]=(float)i10; o[5]=(float)i11; o[6] =(float)i12; o[7] =(float)ity;
    o[8]=(float)i20; o[9]=(float)i21; o[10]=(float)i22; o[11]=(float)itz;
}

// ---------------- Kernel B: transpose [J][D][H][W] -> [D][H][W][NJP] (pad 25->32) ----
__global__ __launch_bounds__(256) void transpose_vox_kernel(const float* __restrict__ vox,
                                                            float* __restrict__ vt) {
    __shared__ float lds[NJ*129];
    int row = blockIdx.x;                  // z*VH + y  (0..4095)
    int t = threadIdx.x;
    for (int idx = t; idx < NJ*VW; idx += 256) {
        int j  = idx >> 7;
        int xx = idx & 127;
        lds[j*129 + xx] = vox[(size_t)j*DHW + (size_t)row*VW + xx];
    }
    __syncthreads();
    float* out = vt + (size_t)row * (VW*NJP);
    for (int idx = t; idx < VW*NJP; idx += 256) {
        int xx = idx >> 5;
        int j  = idx & 31;
        out[idx] = (j < NJ) ? lds[j*129 + xx] : 0.0f;
    }
}

// ---------------- Sort kernels: morton-cell counting sort of points ----------------
__device__ __forceinline__ int cell_of(float v) {       // [-1,1] -> 0..15
    int c = (int)((v + 1.0f) * 8.0f);
    return min(max(c, 0), 15);
}
__device__ __forceinline__ int morton12(int ix, int iy, int iz) {
    int m = 0;
    #pragma unroll
    for (int b = 0; b < 4; ++b)
        m |= (((ix>>b)&1)<<(3*b)) | (((iy>>b)&1)<<(3*b+1)) | (((iz>>b)&1)<<(3*b+2));
    return m;
}
__global__ void zero_hist_kernel(int* hist) {
    int g = blockIdx.x*256 + threadIdx.x;
    if (g < NCELL) hist[g] = 0;
}
__global__ void hist_kernel(const float* __restrict__ x, int* __restrict__ hist, int N) {
    int g = blockIdx.x*256 + threadIdx.x;
    if (g >= N) return;
    int m = morton12(cell_of(x[g*3+0]), cell_of(x[g*3+1]), cell_of(x[g*3+2]));
    atomicAdd(&hist[m], 1);
}
__global__ __launch_bounds__(1024) void scan_kernel(const int* __restrict__ hist,
                                                    int* __restrict__ offs) {
    __shared__ int part[1024];
    int t = threadIdx.x;
    int4 h = ((const int4*)hist)[t];
    int s = h.x + h.y + h.z + h.w;
    part[t] = s;
    __syncthreads();
    for (int off = 1; off < 1024; off <<= 1) {
        int v = (t >= off) ? part[t-off] : 0;
        __syncthreads();
        part[t] += v;
        __syncthreads();
    }
    int excl = part[t] - s;
    offs[4*t+0] = excl;
    offs[4*t+1] = excl + h.x;
    offs[4*t+2] = excl + h.x + h.y;
    offs[4*t+3] = excl + h.x + h.y + h.z;
}
__global__ void scatter_kernel(const float* __restrict__ x, int* __restrict__ offs,
                               int* __restrict__ perm, int N) {
    int g = blockIdx.x*256 + threadIdx.x;
    if (g >= N) return;
    int m = morton12(cell_of(x[g*3+0]), cell_of(x[g*3+1]), cell_of(x[g*3+2]));
    int pos = atomicAdd(&offs[m], 1);
    perm[pos] = g;
}

// ---------------- Kernel C: main per-point deformer ----------------
__device__ __forceinline__ float f4g(const float4 v, int k) {
    return k==0 ? v.x : k==1 ? v.y : k==2 ? v.z : v.w;
}

// per-channel: softmax numerator + folded-warp accumulation.
// M read from global tfs at compile-time offsets -> scalar-cache s_load path.
#define CH_BODY(jj, vv) do {                                              \
    float ev = __expf(TEMP * (vv));                                       \
    s_sum += ev;                                                          \
    const float* M_ = &tfs[(jj)*16];                                      \
    E0 += ev*M_[0]; E1  += ev*M_[1];  E2  += ev*M_[2];  E3  += ev*M_[3];  \
    E4 += ev*M_[4]; E5  += ev*M_[5];  E6  += ev*M_[6];  E7  += ev*M_[7];  \
    E8 += ev*M_[8]; E9  += ev*M_[9];  E10 += ev*M_[10]; E11 += ev*M_[11]; \
    if ((jj) < 15) myE[curOff + (jj)] = ev;                               \
} while (0)

// 4 threads per point; thread `sub` handles inits i = sub, sub+4, ...
// Softmax numerators live in per-thread LDS double-slots (stride 33: conflict-free),
// flipped on argmax-win => no 30-register feature payload.
template<bool VT>
__global__ __launch_bounds__(256, 4) void deformer_kernel(
        const float* __restrict__ x,
        const float* __restrict__ tfs,
        const float* __restrict__ vsrc,
        const float* __restrict__ tinv,
        const int* __restrict__ perm,
        float* __restrict__ out, int N, int ni) {
    __shared__ float s_feat[256*33];           // 33 KB: two 16-float slots + pad per thread
    int t   = threadIdx.x;

    // bijective XCD chunk-swizzle: each XCD gets a contiguous morton range
    int nwg = gridDim.x;
    int q = nwg >> 3, r = nwg & 7;
    int xcd = blockIdx.x & 7, blk = blockIdx.x >> 3;
    int lb = (xcd < r ? xcd*(q+1) : r*(q+1) + (xcd-r)*q) + blk;

    int ns  = lb*64 + (t >> 2);
    int sub = t & 3;
    if (ns >= N) return;
    int n = perm ? perm[ns] : ns;

    float px = x[n*3+0], py = x[n*3+1], pz = x[n*3+2];
    float* myE = &s_feat[t*33];

    float bestD = -3.0e38f;
    int   bestIdx = 0x7fffffff;
    int   curOff = 0, bestOff = 0;
    float bInvs = 1.0f;
    float bcx = 0.f, bcy = 0.f, bcz = 0.f;

    #pragma unroll 1
    for (int i = sub; i < ni; i += 4) {
        const float* Ti = &tinv[i*12];
        float cx = Ti[0]*px + Ti[1]*py + Ti[2] *pz + Ti[3];
        float cy = Ti[4]*px + Ti[5]*py + Ti[6] *pz + Ti[7];
        float cz = Ti[8]*px + Ti[9]*py + Ti[10]*pz + Ti[11];

        float gx = fminf(fmaxf((cx + 1.0f) * (0.5f*(VW-1)), 0.0f), (float)(VW-1));
        float gy = fminf(fmaxf((cy + 1.0f) * (0.5f*(VH-1)), 0.0f), (float)(VH-1));
        float gz = fminf(fmaxf((cz + 1.0f) * (0.5f*(VD-1)), 0.0f), (float)(VD-1));
        int x0 = (int)gx, y0 = (int)gy, z0 = (int)gz;
        int x1 = min(x0+1, VW-1), y1 = min(y0+1, VH-1), z1 = min(z0+1, VD-1);
        float fx = gx - (float)x0, fy = gy - (float)y0, fz = gz - (float)z0;
        float ax = 1.0f - fx, ay = 1.0f - fy, az = 1.0f - fz;
        float w000 = ax*ay*az, w001 = fx*ay*az, w010 = ax*fy*az, w011 = fx*fy*az;
        float w100 = ax*ay*fz, w101 = fx*ay*fz, w110 = ax*fy*fz, w111 = fx*fy*fz;

        float s_sum = 0.0f;
        float E0=0,E1=0,E2=0,E3=0,E4=0,E5=0,E6=0,E7=0,E8=0,E9=0,E10=0,E11=0;

        if (VT) {
            int o000 = ((z0*VH + y0)*VW + x0) * NJP;
            int dz = (z1 - z0) * (VH*VW*NJP);
            int dy = (y1 - y0) * (VW*NJP);
            int dx = (x1 - x0) * NJP;
            int o001 = o000 + dx,      o010 = o000 + dy,      o011 = o000 + dy + dx;
            int o100 = o000 + dz,      o101 = o000 + dz + dx;
            int o110 = o000 + dz + dy, o111 = o000 + dz + dy + dx;

            #pragma unroll
            for (int j4 = 0; j4 < 7; ++j4) {
                const int jb = j4*4;
                float4 a000 = *(const float4*)&vsrc[o000 + jb];
                float4 a001 = *(const float4*)&vsrc[o001 + jb];
                float4 a010 = *(const float4*)&vsrc[o010 + jb];
                float4 a011 = *(const float4*)&vsrc[o011 + jb];
                float4 a100 = *(const float4*)&vsrc[o100 + jb];
                float4 a101 = *(const float4*)&vsrc[o101 + jb];
                float4 a110 = *(const float4*)&vsrc[o110 + jb];
                float4 a111 = *(const float4*)&vsrc[o111 + jb];
                #pragma unroll
                for (int k = 0; k < 4; ++k) {
                    const int j = jb + k;
                    if (j < NJ) {
                        float v = f4g(a000,k)*w000 + f4g(a001,k)*w001
                                + f4g(a010,k)*w010 + f4g(a011,k)*w011
                                + f4g(a100,k)*w100 + f4g(a101,k)*w101
                                + f4g(a110,k)*w110 + f4g(a111,k)*w111;
                        CH_BODY(j, v);
                    }
                }
            }
        } else {
            int b000 = (z0*VH + y0)*VW + x0;
            int dz = (z1 - z0) * (VH*VW);
            int dy = (y1 - y0) * VW;
            int dx = (x1 - x0);
            #pragma unroll
            for (int j = 0; j < NJ; ++j) {
                const float* vj = vsrc + (size_t)j*DHW + b000;
                float v = vj[0]*w000        + vj[dx]*w001
                        + vj[dy]*w010       + vj[dy+dx]*w011
                        + vj[dz]*w100       + vj[dz+dx]*w101
                        + vj[dz+dy]*w110    + vj[dz+dy+dx]*w111;
                CH_BODY(j, v);
            }
        }

        float invs = 1.0f / s_sum;
        float wxp = (E0*cx + E1*cy + E2 *cz + E3 ) * invs;
        float wyp = (E4*cx + E5*cy + E6 *cz + E7 ) * invs;
        float wzp = (E8*cx + E9*cy + E10*cz + E11) * invs;
        float dxp = wxp - px, dyp = wyp - py, dzp = wzp - pz;
        float err = sqrtf(dxp*dxp + dyp*dyp + dzp*dzp);
        float d = (err < 0.1f) ? -err : NEGINF;

        if (d > bestD || (d == bestD && i < bestIdx)) {
            bestD = d; bestIdx = i;
            bestOff = curOff; curOff ^= 16;   // keep winning slot, write next cand elsewhere
            bInvs = invs;
            bcx = cx; bcy = cy; bcz = cz;
        }
    }

    // combine the 4 candidates — argmax with first-index tie-break
    float od = __shfl_xor(bestD, 1); int oi = __shfl_xor(bestIdx, 1);
    if (od > bestD || (od == bestD && oi < bestIdx)) { bestD = od; bestIdx = oi; }
    od = __shfl_xor(bestD, 2); oi = __shfl_xor(bestIdx, 2);
    if (od > bestD || (od == bestD && oi < bestIdx)) { bestD = od; bestIdx = oi; }

    // exactly one of the 4 lanes owns the winning candidate's payload
    if (sub == (bestIdx & 3)) {
        float* o_d = out;                       // [N]
        float* o_f = out + N;                   // [N,15]
        float* o_m = out + (size_t)N*16;        // [N]
        float* o_w = out + (size_t)N*17;        // [N,3]
        o_d[n] = bestD;
        #pragma unroll
        for (int k = 0; k < 15; ++k) o_f[(size_t)n*15 + k] = myE[bestOff + k] * bInvs;
        o_m[n] = (bestD > -9999.0f) ? 1.0f : 0.0f;
        o_w[n*3+0] = bcx; o_w[n*3+1] = bcy; o_w[n*3+2] = bcz;
    }
}

extern "C" void kernel_launch(void* const* d_in, const int* in_sizes, int n_in,
                              void* d_out, int out_size, void* d_ws, size_t ws_size,
                              hipStream_t stream) {
    const float* x     = (const float*)d_in[0];   // [1,N,3]
    const float* tfs   = (const float*)d_in[1];   // [1,25,4,4]
    const float* vox   = (const float*)d_in[2];   // [1,25,32,128,128]
    const int*   bones = (const int*)  d_in[3];   // [14]
    int N  = in_sizes[0] / 3;
    int ni = in_sizes[3];

    float* ws = (float*)d_ws;
    size_t vt_floats = (size_t)DHW * NJP;                      // 16.78M floats = 67.1MB
    // workspace arena map (floats): [vt | tinv(256) | hist(4096) | offs(4096) | perm(N)]
    size_t need_vt   = vt_floats + TINV_FLOATS;
    size_t need_all  = need_vt + NCELL*2 + (size_t)N;

    bool useVT   = ws_size >= need_vt  * sizeof(float);
    bool useSort = ws_size >= need_all * sizeof(float);

    int nblk = (N + 63) / 64;

    if (useVT) {
        float* vt   = ws;
        float* tinv = ws + vt_floats;
        int* hist = (int*)(tinv + TINV_FLOATS);   // starts AFTER the full tinv arena
        int* offs = hist + NCELL;
        int* perm = offs + NCELL;

        hipLaunchKernelGGL(invert_tfs_kernel, dim3(1), dim3(64), 0, stream,
                           tfs, bones, tinv, ni);
        hipLaunchKernelGGL(transpose_vox_kernel, dim3(VD*VH), dim3(256), 0, stream,
                           vox, vt);
        if (useSort) {
            hipLaunchKernelGGL(zero_hist_kernel, dim3((NCELL+255)/256), dim3(256), 0, stream, hist);
            hipLaunchKernelGGL(hist_kernel, dim3((N+255)/256), dim3(256), 0, stream, x, hist, N);
            hipLaunchKernelGGL(scan_kernel, dim3(1), dim3(1024), 0, stream, hist, offs);
            hipLaunchKernelGGL(scatter_kernel, dim3((N+255)/256), dim3(256), 0, stream, x, offs, perm, N);
        }
        hipLaunchKernelGGL((deformer_kernel<true>), dim3(nblk), dim3(256), 0, stream,
                           x, tfs, vt, tinv, useSort ? perm : (const int*)nullptr,
                           (float*)d_out, N, ni);
    } else {
        float* tinv = ws;
        hipLaunchKernelGGL(invert_tfs_kernel, dim3(1), dim3(64), 0, stream,
                           tfs, bones, tinv, ni);
        hipLaunchKernelGGL((deformer_kernel<false>), dim3(nblk), dim3(256), 0, stream,
                           x, tfs, vox, tinv, (const int*)nullptr,
                           (float*)d_out, N, ni);
    }
}

// Round 5
// 257.619 us; speedup vs baseline: 1.8979x; 1.8979x over previous
//
#include <hip/hip_runtime.h>
#include <math.h>

#define NJ 25          // joints (voxel channels)
#define NJP 32         // padded channel stride in transposed layout (128B, float4-aligned)
#define VD 32
#define VH 128
#define VW 128
#define TEMP 20.0f
#define NEGINF (-10000.0f)
#define DHW (VD*VH*VW)        // 524288
#define NCELL 4096            // 16^3 morton cells for the point sort
#define TINV_FLOATS 256

// workspace arena (floats): [tinv 256 | hist 4096 | offs 4096 | perm N | vt 16.78M]
// small buffers FIRST so sort availability == VT availability (no silent skip).

// ---------------- Kernel A: invert the 14 init-bone affine transforms ----------------
__global__ void invert_tfs_kernel(const float* __restrict__ tfs,
                                  const int* __restrict__ bones,
                                  float* __restrict__ tinv, int ni) {
    int t = threadIdx.x;
    if (t >= ni) return;
    const float* T = tfs + (size_t)bones[t] * 16;
    double r00=T[0], r01=T[1], r02=T[2],  tx=T[3];
    double r10=T[4], r11=T[5], r12=T[6],  ty=T[7];
    double r20=T[8], r21=T[9], r22=T[10], tz=T[11];
    double c00 = r11*r22 - r12*r21;
    double c01 = r12*r20 - r10*r22;
    double c02 = r10*r21 - r11*r20;
    double det = r00*c00 + r01*c01 + r02*c02;
    double id  = 1.0/det;
    double i00 = c00*id;
    double i01 = (r02*r21 - r01*r22)*id;
    double i02 = (r01*r12 - r02*r11)*id;
    double i10 = c01*id;
    double i11 = (r00*r22 - r02*r20)*id;
    double i12 = (r02*r10 - r00*r12)*id;
    double i20 = c02*id;
    double i21 = (r01*r20 - r00*r21)*id;
    double i22 = (r00*r11 - r01*r10)*id;
    double itx = -(i00*tx + i01*ty + i02*tz);
    double ity = -(i10*tx + i11*ty + i12*tz);
    double itz = -(i20*tx + i21*ty + i22*tz);
    float* o = tinv + t*12;
    o[0]=(float)i00; o[1]=(float)i01; o[2] =(float)i02; o[3] =(float)itx;
    o[4]=(float)i10; o[5]=(float)i11; o[6] =(float)i12; o[7] =(float)ity;
    o[8]=(float)i20; o[9]=(float)i21; o[10]=(float)i22; o[11]=(float)itz;
}

// ---------------- Kernel B: transpose [J][D][H][W] -> [D][H][W][NJP] (pad 25->32) ----
__global__ __launch_bounds__(256) void transpose_vox_kernel(const float* __restrict__ vox,
                                                            float* __restrict__ vt) {
    __shared__ float lds[NJ*129];
    int row = blockIdx.x;                  // z*VH + y  (0..4095)
    int t = threadIdx.x;
    for (int idx = t; idx < NJ*VW; idx += 256) {
        int j  = idx >> 7;
        int xx = idx & 127;
        lds[j*129 + xx] = vox[(size_t)j*DHW + (size_t)row*VW + xx];
    }
    __syncthreads();
    float* out = vt + (size_t)row * (VW*NJP);
    for (int idx = t; idx < VW*NJP; idx += 256) {
        int xx = idx >> 5;
        int j  = idx & 31;
        out[idx] = (j < NJ) ? lds[j*129 + xx] : 0.0f;
    }
}

// ---------------- Sort kernels: morton-cell counting sort of points ----------------
__device__ __forceinline__ int cell_of(float v) {       // [-1,1] -> 0..15
    int c = (int)((v + 1.0f) * 8.0f);
    return min(max(c, 0), 15);
}
__device__ __forceinline__ int morton12(int ix, int iy, int iz) {
    int m = 0;
    #pragma unroll
    for (int b = 0; b < 4; ++b)
        m |= (((ix>>b)&1)<<(3*b)) | (((iy>>b)&1)<<(3*b+1)) | (((iz>>b)&1)<<(3*b+2));
    return m;
}
__global__ void zero_hist_kernel(int* hist) {
    int g = blockIdx.x*256 + threadIdx.x;
    if (g < NCELL) hist[g] = 0;
}
__global__ void hist_kernel(const float* __restrict__ x, int* __restrict__ hist, int N) {
    int g = blockIdx.x*256 + threadIdx.x;
    if (g >= N) return;
    int m = morton12(cell_of(x[g*3+0]), cell_of(x[g*3+1]), cell_of(x[g*3+2]));
    atomicAdd(&hist[m], 1);
}
__global__ __launch_bounds__(1024) void scan_kernel(const int* __restrict__ hist,
                                                    int* __restrict__ offs) {
    __shared__ int part[1024];
    int t = threadIdx.x;
    int4 h = ((const int4*)hist)[t];
    int s = h.x + h.y + h.z + h.w;
    part[t] = s;
    __syncthreads();
    for (int off = 1; off < 1024; off <<= 1) {
        int v = (t >= off) ? part[t-off] : 0;
        __syncthreads();
        part[t] += v;
        __syncthreads();
    }
    int excl = part[t] - s;
    offs[4*t+0] = excl;
    offs[4*t+1] = excl + h.x;
    offs[4*t+2] = excl + h.x + h.y;
    offs[4*t+3] = excl + h.x + h.y + h.z;
}
__global__ void scatter_kernel(const float* __restrict__ x, int* __restrict__ offs,
                               int* __restrict__ perm, int N) {
    int g = blockIdx.x*256 + threadIdx.x;
    if (g >= N) return;
    int m = morton12(cell_of(x[g*3+0]), cell_of(x[g*3+1]), cell_of(x[g*3+2]));
    int pos = atomicAdd(&offs[m], 1);
    perm[pos] = g;
}

// ---------------- Kernel C: main per-point deformer ----------------
__device__ __forceinline__ float f4g(const float4 v, int k) {
    return k==0 ? v.x : k==1 ? v.y : k==2 ? v.z : v.w;
}

// per-channel: softmax numerator + folded-warp accumulation.
// M read from global tfs at compile-time offsets -> scalar-cache s_load path.
#define CH_BODY(jj, vv) do {                                              \
    float ev = __expf(TEMP * (vv));                                       \
    s_sum += ev;                                                          \
    const float* M_ = &tfs[(jj)*16];                                      \
    E0 += ev*M_[0]; E1  += ev*M_[1];  E2  += ev*M_[2];  E3  += ev*M_[3];  \
    E4 += ev*M_[4]; E5  += ev*M_[5];  E6  += ev*M_[6];  E7  += ev*M_[7];  \
    E8 += ev*M_[8]; E9  += ev*M_[9];  E10 += ev*M_[10]; E11 += ev*M_[11]; \
    if ((jj) < 15) myE[curOff + (jj)] = ev;                               \
} while (0)

// 2 threads per point; thread `sub` handles inits i = sub, sub+2, ... (7 each, no waste)
// Softmax numerators live in per-thread LDS double-slots (stride 33: conflict-free),
// flipped on argmax-win => no 30-register feature payload.
// NOTE: plain __launch_bounds__(256) — NO min-waves arg. Round-4's (256,4) forced
// VGPR=64 and spilled 577MB to scratch (+60% time). Let the allocator float.
template<bool VT>
__global__ __launch_bounds__(256) void deformer_kernel(
        const float* __restrict__ x,
        const float* __restrict__ tfs,
        const float* __restrict__ vsrc,
        const float* __restrict__ tinv,
        const int* __restrict__ perm,
        float* __restrict__ out, int N, int ni) {
    __shared__ float s_feat[256*33];           // 33 KB: two 16-float slots + pad per thread
    int t   = threadIdx.x;

    // bijective XCD chunk-swizzle: each XCD gets a contiguous morton range
    int nwg = gridDim.x;
    int q = nwg >> 3, r = nwg & 7;
    int xcd = blockIdx.x & 7, blk = blockIdx.x >> 3;
    int lb = (xcd < r ? xcd*(q+1) : r*(q+1) + (xcd-r)*q) + blk;

    int ns  = lb*128 + (t >> 1);               // 128 points per block
    int sub = t & 1;
    if (ns >= N) return;
    int n = perm ? perm[ns] : ns;

    float px = x[n*3+0], py = x[n*3+1], pz = x[n*3+2];
    float* myE = &s_feat[t*33];

    float bestD = -3.0e38f;
    int   bestIdx = 0x7fffffff;
    int   curOff = 0, bestOff = 0;
    float bInvs = 1.0f;
    float bcx = 0.f, bcy = 0.f, bcz = 0.f;

    #pragma unroll 1
    for (int i = sub; i < ni; i += 2) {
        const float* Ti = &tinv[i*12];
        float cx = Ti[0]*px + Ti[1]*py + Ti[2] *pz + Ti[3];
        float cy = Ti[4]*px + Ti[5]*py + Ti[6] *pz + Ti[7];
        float cz = Ti[8]*px + Ti[9]*py + Ti[10]*pz + Ti[11];

        float gx = fminf(fmaxf((cx + 1.0f) * (0.5f*(VW-1)), 0.0f), (float)(VW-1));
        float gy = fminf(fmaxf((cy + 1.0f) * (0.5f*(VH-1)), 0.0f), (float)(VH-1));
        float gz = fminf(fmaxf((cz + 1.0f) * (0.5f*(VD-1)), 0.0f), (float)(VD-1));
        int x0 = (int)gx, y0 = (int)gy, z0 = (int)gz;
        int x1 = min(x0+1, VW-1), y1 = min(y0+1, VH-1), z1 = min(z0+1, VD-1);
        float fx = gx - (float)x0, fy = gy - (float)y0, fz = gz - (float)z0;
        float ax = 1.0f - fx, ay = 1.0f - fy, az = 1.0f - fz;
        float w000 = ax*ay*az, w001 = fx*ay*az, w010 = ax*fy*az, w011 = fx*fy*az;
        float w100 = ax*ay*fz, w101 = fx*ay*fz, w110 = ax*fy*fz, w111 = fx*fy*fz;

        float s_sum = 0.0f;
        float E0=0,E1=0,E2=0,E3=0,E4=0,E5=0,E6=0,E7=0,E8=0,E9=0,E10=0,E11=0;

        if (VT) {
            int o000 = ((z0*VH + y0)*VW + x0) * NJP;
            int dz = (z1 - z0) * (VH*VW*NJP);
            int dy = (y1 - y0) * (VW*NJP);
            int dx = (x1 - x0) * NJP;
            int o001 = o000 + dx,      o010 = o000 + dy,      o011 = o000 + dy + dx;
            int o100 = o000 + dz,      o101 = o000 + dz + dx;
            int o110 = o000 + dz + dy, o111 = o000 + dz + dy + dx;

            #pragma unroll
            for (int j4 = 0; j4 < 7; ++j4) {
                const int jb = j4*4;
                float4 a000 = *(const float4*)&vsrc[o000 + jb];
                float4 a001 = *(const float4*)&vsrc[o001 + jb];
                float4 a010 = *(const float4*)&vsrc[o010 + jb];
                float4 a011 = *(const float4*)&vsrc[o011 + jb];
                float4 a100 = *(const float4*)&vsrc[o100 + jb];
                float4 a101 = *(const float4*)&vsrc[o101 + jb];
                float4 a110 = *(const float4*)&vsrc[o110 + jb];
                float4 a111 = *(const float4*)&vsrc[o111 + jb];
                #pragma unroll
                for (int k = 0; k < 4; ++k) {
                    const int j = jb + k;
                    if (j < NJ) {
                        float v = f4g(a000,k)*w000 + f4g(a001,k)*w001
                                + f4g(a010,k)*w010 + f4g(a011,k)*w011
                                + f4g(a100,k)*w100 + f4g(a101,k)*w101
                                + f4g(a110,k)*w110 + f4g(a111,k)*w111;
                        CH_BODY(j, v);
                    }
                }
            }
        } else {
            int b000 = (z0*VH + y0)*VW + x0;
            int dz = (z1 - z0) * (VH*VW);
            int dy = (y1 - y0) * VW;
            int dx = (x1 - x0);
            #pragma unroll
            for (int j = 0; j < NJ; ++j) {
                const float* vj = vsrc + (size_t)j*DHW + b000;
                float v = vj[0]*w000        + vj[dx]*w001
                        + vj[dy]*w010       + vj[dy+dx]*w011
                        + vj[dz]*w100       + vj[dz+dx]*w101
                        + vj[dz+dy]*w110    + vj[dz+dy+dx]*w111;
                CH_BODY(j, v);
            }
        }

        float invs = 1.0f / s_sum;
        float wxp = (E0*cx + E1*cy + E2 *cz + E3 ) * invs;
        float wyp = (E4*cx + E5*cy + E6 *cz + E7 ) * invs;
        float wzp = (E8*cx + E9*cy + E10*cz + E11) * invs;
        float dxp = wxp - px, dyp = wyp - py, dzp = wzp - pz;
        float err = sqrtf(dxp*dxp + dyp*dyp + dzp*dzp);
        float d = (err < 0.1f) ? -err : NEGINF;

        if (d > bestD || (d == bestD && i < bestIdx)) {
            bestD = d; bestIdx = i;
            bestOff = curOff; curOff ^= 16;   // keep winning slot, write next cand elsewhere
            bInvs = invs;
            bcx = cx; bcy = cy; bcz = cz;
        }
    }

    // combine the 2 candidates — argmax with first-index tie-break
    float od = __shfl_xor(bestD, 1); int oi = __shfl_xor(bestIdx, 1);
    if (od > bestD || (od == bestD && oi < bestIdx)) { bestD = od; bestIdx = oi; }

    // exactly one of the 2 lanes owns the winning candidate's payload
    if (sub == (bestIdx & 1)) {
        float* o_d = out;                       // [N]
        float* o_f = out + N;                   // [N,15]
        float* o_m = out + (size_t)N*16;        // [N]
        float* o_w = out + (size_t)N*17;        // [N,3]
        o_d[n] = bestD;
        #pragma unroll
        for (int k = 0; k < 15; ++k) o_f[(size_t)n*15 + k] = myE[bestOff + k] * bInvs;
        o_m[n] = (bestD > -9999.0f) ? 1.0f : 0.0f;
        o_w[n*3+0] = bcx; o_w[n*3+1] = bcy; o_w[n*3+2] = bcz;
    }
}

extern "C" void kernel_launch(void* const* d_in, const int* in_sizes, int n_in,
                              void* d_out, int out_size, void* d_ws, size_t ws_size,
                              hipStream_t stream) {
    const float* x     = (const float*)d_in[0];   // [1,N,3]
    const float* tfs   = (const float*)d_in[1];   // [1,25,4,4]
    const float* vox   = (const float*)d_in[2];   // [1,25,32,128,128]
    const int*   bones = (const int*)  d_in[3];   // [14]
    int N  = in_sizes[0] / 3;
    int ni = in_sizes[3];

    float* ws = (float*)d_ws;
    // arena (floats): [tinv 256 | hist 4096 | offs 4096 | perm N | vt 16.78M]
    size_t vt_off    = (size_t)TINV_FLOATS + NCELL*2 + (size_t)N;   // 69984 (128B-aligned)
    size_t vt_floats = (size_t)DHW * NJP;
    size_t need_all  = vt_off + vt_floats;

    float* tinv = ws;
    int*   hist = (int*)(ws + TINV_FLOATS);
    int*   offs = hist + NCELL;
    int*   perm = offs + NCELL;
    float* vt   = ws + vt_off;

    bool useVT = ws_size >= need_all * sizeof(float);
    int nblk = (N + 127) / 128;

    hipLaunchKernelGGL(invert_tfs_kernel, dim3(1), dim3(64), 0, stream,
                       tfs, bones, tinv, ni);
    if (useVT) {
        hipLaunchKernelGGL(transpose_vox_kernel, dim3(VD*VH), dim3(256), 0, stream,
                           vox, vt);
        hipLaunchKernelGGL(zero_hist_kernel, dim3((NCELL+255)/256), dim3(256), 0, stream, hist);
        hipLaunchKernelGGL(hist_kernel, dim3((N+255)/256), dim3(256), 0, stream, x, hist, N);
        hipLaunchKernelGGL(scan_kernel, dim3(1), dim3(1024), 0, stream, hist, offs);
        hipLaunchKernelGGL(scatter_kernel, dim3((N+255)/256), dim3(256), 0, stream, x, offs, perm, N);
        hipLaunchKernelGGL((deformer_kernel<true>), dim3(nblk), dim3(256), 0, stream,
                           x, tfs, vt, tinv, perm, (float*)d_out, N, ni);
    } else {
        hipLaunchKernelGGL((deformer_kernel<false>), dim3(nblk), dim3(256), 0, stream,
                           x, tfs, vox, tinv, (const int*)nullptr,
                           (float*)d_out, N, ni);
    }
}